// Round 7
// baseline (131.665 us; speedup 1.0000x reference)
//
#include <hip/hip_runtime.h>

// Problem constants (fixed by setup_inputs in the reference)
#define B_  8
#define T_  2048
#define D_  1024
#define H_  8
#define S_  128
#define NSPAN (B_ * S_)
#define NBLK  256      // persistent workers, 1/CU (LDS-limited), dynamic queue

// --------------------------------------------------------------------------
// R14 (v6) = v5 with ONE change: __launch_bounds__(1024, 1).
//  - R6 evidence: v5 at __launch_bounds__(1024,4) compiled to VGPR_Count=64
//    and spilled (WRITE_SIZE 19.5 MB vs 4.5 useful; dur 46 us, VALUBusy 16%).
//    kwr alone needs 64 VGPRs; ~120 live total.
//  - Diagnosis (2 data points: R2's (512,4)->64 and R6's (1024,4)->64): the
//    2nd launch_bounds arg behaves like CUDA min-BLOCKS-per-CU on this
//    toolchain: 4 blocks x 16 waves = 64 waves/CU clamped to 32 -> 8
//    waves/SIMD -> 64-VGPR cap. (1024,1): 16 waves/CU -> 4/SIMD -> 128 cap.
//  - LDS 129.5 KB already limits to 1 block/CU, so occupancy is unchanged;
//    only the register budget doubles.
//  - R6 also showed FETCH=37 MB ~= unique row footprint (L3 serves span
//    overlap): HBM floor ~6 us, LDS pipe ~4.4 us, VALU ~2 us -> expect
//    kernel 13-18 us.
//
// v5 design (proven correct, absmax 0.0039):
//  - kw in REGISTERS (wave pair p=0: heads 0-3, p=1: heads 4-7; 64 VGPR),
//    rows in LDS rowbuf (needed for phase3 anyway). Dot reads partner's
//    half-row from LDS: 32 ds_reads/row (v4) -> 4W+4R per row.
//  - Dynamic span queue (atomic in ws; poison unconditional per R8/R9);
//    pop at loop top into alternating LDS slot; 2-slot register prefetch
//    of next span covers the softmax/phase3 HBM gap.
//  - Phase3: 256 threads x float4, weights via LDS broadcast.
// --------------------------------------------------------------------------

__global__ void init_counter(unsigned int* __restrict__ c) { *c = 0u; }

__global__ __launch_bounds__(1024, 1) void span_pool_v6(
    const float* __restrict__ feat,    // [B*T, D]
    const int* __restrict__ begins,    // [B*S]
    const int* __restrict__ ends,      // [B*S]
    const float* __restrict__ kw,      // [H, D]
    const float* __restrict__ kb,      // [H]
    float* __restrict__ out,           // [B*S, D]
    unsigned int* __restrict__ counter)
{
    const int tid  = threadIdx.x;
    const int wv   = tid >> 6;              // 0..15
    const int lane = tid & 63;
    const int w    = wv >> 1;               // row-slot base 0..7
    const int p    = wv & 1;                // head-half: 0 -> heads 0-3, 1 -> 4-7
    const int coff = p * 512 + lane * 4;    // my half-row columns

    __shared__ __align__(16) float rowbuf[32 * D_];   // 128 KB span rows
    __shared__ __align__(16) float wts[32 * H_];      // 1 KB logits->weights
    __shared__ unsigned int s_slot[2];

    // kw for my 4 heads, full D, in registers (statically indexed only)
    float4 kwr[4][4];
#pragma unroll
    for (int h = 0; h < 4; ++h)
#pragma unroll
        for (int c = 0; c < 4; ++c)
            kwr[h][c] = *(const float4*)(kw + (size_t)(4*p + h) * D_ + c * 256 + lane * 4);

    const float kbq = kb[4*p + (lane & 3)];

    // dot one row-slot: my half (ra,rb) from regs, other half from rowbuf
    auto dot_slot = [&](int r, float4 ra, float4 rb) {
        const float* rbo = &rowbuf[r * D_ + (p ? 0 : 512) + lane * 4];
        float4 fo0 = *(const float4*)(rbo);
        float4 fo1 = *(const float4*)(rbo + 256);
        const float4 f0 = p ? fo0 : ra;
        const float4 f1 = p ? fo1 : rb;
        const float4 f2 = p ? ra  : fo0;
        const float4 f3 = p ? rb  : fo1;
        float acc[4];
#pragma unroll
        for (int h = 0; h < 4; ++h) {
            acc[h] = f0.x*kwr[h][0].x + f0.y*kwr[h][0].y + f0.z*kwr[h][0].z + f0.w*kwr[h][0].w
                   + f1.x*kwr[h][1].x + f1.y*kwr[h][1].y + f1.z*kwr[h][1].z + f1.w*kwr[h][1].w
                   + f2.x*kwr[h][2].x + f2.y*kwr[h][2].y + f2.z*kwr[h][2].z + f2.w*kwr[h][2].w
                   + f3.x*kwr[h][3].x + f3.y*kwr[h][3].y + f3.z*kwr[h][3].z + f3.w*kwr[h][3].w;
        }
        // value-compacting reduce (4 values over lane bits 0..1, then xor 4..32)
        const bool hb = lane & 1;
        float mine  = hb ? acc[1] : acc[0];
        float other = hb ? acc[0] : acc[1];
        float t0 = mine + __shfl_xor(other, 1, 64);
        mine  = hb ? acc[3] : acc[2];
        other = hb ? acc[2] : acc[3];
        float t1 = mine + __shfl_xor(other, 1, 64);
        const bool hb2 = (lane >> 1) & 1;
        mine  = hb2 ? t1 : t0;
        other = hb2 ? t0 : t1;
        float r0 = mine + __shfl_xor(other, 2, 64);
        r0 += __shfl_xor(r0,  4, 64);
        r0 += __shfl_xor(r0,  8, 64);
        r0 += __shfl_xor(r0, 16, 64);
        r0 += __shfl_xor(r0, 32, 64);
        if (lane < 4) wts[r * H_ + 4*p + lane] = r0 + kbq;   // head 4p+lane
    };

    // ---- prologue: pop first span, prefetch slots 0,1 (rows w, w+8)
    if (tid == 0) s_slot[0] = atomicAdd(counter, 1u);
    __syncthreads();
    int s = (int)s_slot[0];
    bool have = (s < NSPAN);
    int width = 0; size_t row0 = 0;
    float4 pfa0, pfa1, pfb0, pfb1;
    if (have) {
        const int bg = begins[s];
        width = ends[s] - bg;               // 1..32, rows always in-bounds
        row0  = (size_t)(s >> 7) * T_ + bg;
        if (w < width) {
            const float* fr = feat + (row0 + w) * D_ + coff;
            pfa0 = *(const float4*)(fr); pfa1 = *(const float4*)(fr + 256);
        }
        if (w + 8 < width) {
            const float* fr = feat + (row0 + w + 8) * D_ + coff;
            pfb0 = *(const float4*)(fr); pfb1 = *(const float4*)(fr + 256);
        }
    }

    int it = 0;
    while (have) {
        // pop NEXT span at loop top: atomic latency hides under sweep1+dot
        if (tid == 0) s_slot[(it + 1) & 1] = atomicAdd(counter, 1u);

        // ---- sweep1: issue far-slot loads, stash all my row-halves
        float4 g2a, g2b, g3a, g3b;
        const bool v2 = (w + 16) < width, v3 = (w + 24) < width;
        if (v2) { const float* fr = feat + (row0 + w + 16) * D_ + coff;
                  g2a = *(const float4*)(fr); g2b = *(const float4*)(fr + 256); }
        if (v3) { const float* fr = feat + (row0 + w + 24) * D_ + coff;
                  g3a = *(const float4*)(fr); g3b = *(const float4*)(fr + 256); }
        if (w < width) {
            float* rb = &rowbuf[w * D_ + coff];
            *(float4*)(rb) = pfa0; *(float4*)(rb + 256) = pfa1;
        }
        if (w + 8 < width) {
            float* rb = &rowbuf[(w + 8) * D_ + coff];
            *(float4*)(rb) = pfb0; *(float4*)(rb + 256) = pfb1;
        }
        if (v2) { float* rb = &rowbuf[(w + 16) * D_ + coff];
                  *(float4*)(rb) = g2a; *(float4*)(rb + 256) = g2b; }
        if (v3) { float* rb = &rowbuf[(w + 24) * D_ + coff];
                  *(float4*)(rb) = g3a; *(float4*)(rb + 256) = g3b; }
        __syncthreads();                    // (B1) rowbuf complete

        // ---- sweep2: dot my 4 row-slots (kw from regs, other half from LDS)
        if (w < width)      dot_slot(w,      pfa0, pfa1);
        if (w + 8 < width)  dot_slot(w + 8,  pfb0, pfb1);
        if (v2)             dot_slot(w + 16, g2a, g2b);
        if (v3)             dot_slot(w + 24, g3a, g3b);
        __syncthreads();                    // (B2) wts complete; next pop visible

        // ---- read next span; issue its prefetch NOW (flies over softmax+p3)
        const int snext = (int)s_slot[(it + 1) & 1];
        const bool havenext = (snext < NSPAN);
        int width_n = 0; size_t row0_n = 0;
        if (havenext) {
            const int bg = begins[snext];
            width_n = ends[snext] - bg;
            row0_n  = (size_t)(snext >> 7) * T_ + bg;
            if (w < width_n) {
                const float* fr = feat + (row0_n + w) * D_ + coff;
                pfa0 = *(const float4*)(fr); pfa1 = *(const float4*)(fr + 256);
            }
            if (w + 8 < width_n) {
                const float* fr = feat + (row0_n + w + 8) * D_ + coff;
                pfb0 = *(const float4*)(fr); pfb1 = *(const float4*)(fr + 256);
            }
        }

        // ---- wave-0 register softmax over wts (proven, in place)
        if (tid < 64) {
            float4 lv = *(const float4*)&wts[lane * 4];
            const int w8 = width * H_;
            float v0 = (4 * lane + 0 < w8) ? lv.x : -1e30f;
            float v1 = (4 * lane + 1 < w8) ? lv.y : -1e30f;
            float v2s = (4 * lane + 2 < w8) ? lv.z : -1e30f;
            float v3s = (4 * lane + 3 < w8) ? lv.w : -1e30f;

            float m0 = v0, m1 = v1, m2 = v2s, m3 = v3s;
#pragma unroll
            for (int off = 2; off <= 32; off <<= 1) {
                m0 = fmaxf(m0, __shfl_xor(m0, off, 64));
                m1 = fmaxf(m1, __shfl_xor(m1, off, 64));
                m2 = fmaxf(m2, __shfl_xor(m2, off, 64));
                m3 = fmaxf(m3, __shfl_xor(m3, off, 64));
            }
            float e0 = __expf(v0 - m0);     // masked -> exactly 0
            float e1 = __expf(v1 - m1);
            float e2 = __expf(v2s - m2);
            float e3 = __expf(v3s - m3);
            float s0 = e0, s1 = e1, s2 = e2, s3 = e3;
#pragma unroll
            for (int off = 2; off <= 32; off <<= 1) {
                s0 += __shfl_xor(s0, off, 64);
                s1 += __shfl_xor(s1, off, 64);
                s2 += __shfl_xor(s2, off, 64);
                s3 += __shfl_xor(s3, off, 64);
            }
            *(float4*)&wts[lane * 4] =
                make_float4(e0 / s0, e1 / s1, e2 / s2, e3 / s3);
        }
        __syncthreads();                    // (C) weights ready

        // ---- phase 3: threads 0..255, thread t owns cols 4t..4t+3 (one head)
        if (tid < 256) {
            const int ha = tid >> 5;        // head of cols 4t..4t+3
            float4 a = make_float4(0.f, 0.f, 0.f, 0.f);
#pragma unroll 4
            for (int k = 0; k < width; ++k) {
                const float4 rv = *(const float4*)&rowbuf[k * D_ + tid * 4];
                const float wt = wts[k * H_ + ha];
                a.x += wt * rv.x; a.y += wt * rv.y;
                a.z += wt * rv.z; a.w += wt * rv.w;
            }
            *(float4*)(out + (size_t)s * D_ + tid * 4) = a;
        }
        __syncthreads();                    // (A) rowbuf/wts free for next stash

        s = snext; have = havenext; width = width_n; row0 = row0_n; ++it;
    }
}

extern "C" void kernel_launch(void* const* d_in, const int* in_sizes, int n_in,
                              void* d_out, int out_size, void* d_ws, size_t ws_size,
                              hipStream_t stream) {
    const float* feat   = (const float*)d_in[0];   // features f32 [B,T,D]
    const int*   begins = (const int*)d_in[1];     // int32 [B,S]
    const int*   ends   = (const int*)d_in[2];     // int32 [B,S]
    const float* kw     = (const float*)d_in[3];   // key_w f32 [H,D]
    const float* kb     = (const float*)d_in[4];   // key_b f32 [H]
    float*       out    = (float*)d_out;           // f32 [B*S, D]
    unsigned int* counter = (unsigned int*)d_ws;   // 4 B of ws (poison unconditional)

    init_counter<<<1, 1, 0, stream>>>(counter);
    span_pool_v6<<<NBLK, 1024, 0, stream>>>(feat, begins, ends, kw, kb, out, counter);
}

// Round 8
// 120.961 us; speedup vs baseline: 1.0885x; 1.0885x over previous
//
#include <hip/hip_runtime.h>

// Problem constants (fixed by setup_inputs in the reference)
#define B_  8
#define T_  2048
#define D_  1024
#define H_  8
#define S_  128
#define NSPAN (B_ * S_)
#define NBLK  256      // persistent workers, 1/CU (LDS-limited), dynamic queue

// --------------------------------------------------------------------------
// R15 (v7): fit the allocator's 64-VGPR budget instead of fighting it.
//  - R6/R7 evidence: 1024-thread kernels get VGPR_Count=64 regardless of
//    __launch_bounds__ 2nd arg ((1024,4) and (1024,1) -> identical binary,
//    WRITE 19.5 MB spills, 46 us). Backend heuristic pins 8 waves/EU.
//  - v7 halves register demand: wave quad p holds kw for 2 HEADS (32 VGPR,
//    was 4 heads/64). 16 waves = 4 row-groups x 4 head-quads. Group g owns
//    rows == g (mod 4); wave (g,p) stashes quarter p of those rows; dot
//    reads all 4 quarters from LDS (row regs die at stash -> low pressure).
//  - Reduce batches 2 rows x 2 heads (7 shuffles per row-pair).
//  - Live-reg audit: sweep1 32+8+12=52..58, sweep2 32+16+4=52..58,
//    phase3 ~50. Peak ~60 < 64 -> no scratch.
//  - LDS/CU per span-row: 4 stash + 16 dot-reads (b128) + 14 shuffles;
//    + phase3 ~5 ops/row. ~10 us busy, overlaps ~6-10 us HBM (R6: FETCH
//    37 MB = unique footprint, L3 dedupes span overlap).
//  - Queue, prefetch timing, softmax, phase3 carried verbatim from v5/v6
//    (proven correct: absmax 0.0039).
//  - Validation targets: WRITE_SIZE ~4.5 MB (spills gone), kernel 12-16 us.
// --------------------------------------------------------------------------

__global__ void init_counter(unsigned int* __restrict__ c) { *c = 0u; }

__device__ __forceinline__ float dot4(float4 a, float4 b) {
    return a.x*b.x + a.y*b.y + a.z*b.z + a.w*b.w;
}

__global__ __launch_bounds__(1024) void span_pool_v7(
    const float* __restrict__ feat,    // [B*T, D]
    const int* __restrict__ begins,    // [B*S]
    const int* __restrict__ ends,      // [B*S]
    const float* __restrict__ kw,      // [H, D]
    const float* __restrict__ kb,      // [H]
    float* __restrict__ out,           // [B*S, D]
    unsigned int* __restrict__ counter)
{
    const int tid  = threadIdx.x;
    const int wv   = tid >> 6;              // 0..15
    const int lane = tid & 63;
    const int g    = wv >> 2;               // row-group 0..3: rows == g (mod 4)
    const int p    = wv & 3;                // head-quad: heads 2p, 2p+1
    const int coff = p * 256 + lane * 4;    // my quarter-row columns

    __shared__ __align__(16) float rowbuf[32 * D_];   // 128 KB span rows
    __shared__ __align__(16) float wts[32 * H_];      // 1 KB logits->weights
    __shared__ unsigned int s_slot[2];

    // kw for my 2 heads, full D, in registers (32 VGPR, statically indexed)
    float4 kwr[2][4];
#pragma unroll
    for (int h = 0; h < 2; ++h)
#pragma unroll
        for (int c = 0; c < 4; ++c)
            kwr[h][c] = *(const float4*)(kw + (size_t)(2*p + h) * D_ + c * 256 + lane * 4);

    const float kbq = kb[2*p + (lane & 1)];

    // dot a row-pair (rA, rA+4): 2 heads each, all quarters from rowbuf.
    // After 7-shuffle compact+tree: lane<4 holds (row rA+4*(lane>>1),
    // head 2p+(lane&1)). Rows >= width produce garbage, never written.
    auto dot_pair = [&](int rA, int width) {
        const int rB = rA + 4;
        float aA0 = 0.f, aA1 = 0.f, aB0 = 0.f, aB1 = 0.f;
#pragma unroll
        for (int c = 0; c < 4; ++c) {
            const float4 fa = *(const float4*)&rowbuf[rA * D_ + c * 256 + lane * 4];
            aA0 += dot4(fa, kwr[0][c]);
            aA1 += dot4(fa, kwr[1][c]);
        }
#pragma unroll
        for (int c = 0; c < 4; ++c) {
            const float4 fb = *(const float4*)&rowbuf[rB * D_ + c * 256 + lane * 4];
            aB0 += dot4(fb, kwr[0][c]);
            aB1 += dot4(fb, kwr[1][c]);
        }
        const bool h0 = lane & 1;
        float mA = h0 ? aA1 : aA0, oA = h0 ? aA0 : aA1;
        float tA = mA + __shfl_xor(oA, 1, 64);
        float mB = h0 ? aB1 : aB0, oB = h0 ? aB0 : aB1;
        float tB = mB + __shfl_xor(oB, 1, 64);
        const bool h1 = (lane >> 1) & 1;
        float mT = h1 ? tB : tA, oT = h1 ? tA : tB;
        float t = mT + __shfl_xor(oT, 2, 64);
        t += __shfl_xor(t,  4, 64);
        t += __shfl_xor(t,  8, 64);
        t += __shfl_xor(t, 16, 64);
        t += __shfl_xor(t, 32, 64);
        if (lane < 4) {
            const int rw = rA + 4 * (lane >> 1);
            if (rw < width)
                wts[rw * H_ + 2*p + (lane & 1)] = t + kbq;
        }
    };

    // ---- prologue: pop first span, prefetch rows g, g+4 (quarter p)
    if (tid == 0) s_slot[0] = atomicAdd(counter, 1u);
    __syncthreads();
    int s = (int)s_slot[0];
    bool have = (s < NSPAN);
    int width = 0; size_t row0 = 0;
    float4 pf0, pf1;
    if (have) {
        const int bg = begins[s];
        width = ends[s] - bg;               // 1..32, rows always in-bounds
        row0  = (size_t)(s >> 7) * T_ + bg;
        if (g < width)     pf0 = *(const float4*)(feat + (row0 + g)     * D_ + coff);
        if (g + 4 < width) pf1 = *(const float4*)(feat + (row0 + g + 4) * D_ + coff);
    }

    int it = 0;
    while (have) {
        // pop NEXT span at loop top: atomic latency hides under sweep1+dot
        if (tid == 0) s_slot[(it + 1) & 1] = atomicAdd(counter, 1u);

        // ---- sweep1: stash prefetched rows; load+stash rows g+8..g+28
        if (g < width)     { *(float4*)&rowbuf[(g)     * D_ + coff] = pf0; }
        if (g + 4 < width) { *(float4*)&rowbuf[(g + 4) * D_ + coff] = pf1; }
        {   // batch 1: rows g+8, g+12, g+16 (loads issued together for MLP)
            float4 t0, t1, t2;
            const bool b0 = g +  8 < width, b1 = g + 12 < width, b2 = g + 16 < width;
            if (b0) t0 = *(const float4*)(feat + (row0 + g +  8) * D_ + coff);
            if (b1) t1 = *(const float4*)(feat + (row0 + g + 12) * D_ + coff);
            if (b2) t2 = *(const float4*)(feat + (row0 + g + 16) * D_ + coff);
            if (b0) *(float4*)&rowbuf[(g +  8) * D_ + coff] = t0;
            if (b1) *(float4*)&rowbuf[(g + 12) * D_ + coff] = t1;
            if (b2) *(float4*)&rowbuf[(g + 16) * D_ + coff] = t2;
        }
        {   // batch 2: rows g+20, g+24, g+28
            float4 t0, t1, t2;
            const bool b0 = g + 20 < width, b1 = g + 24 < width, b2 = g + 28 < width;
            if (b0) t0 = *(const float4*)(feat + (row0 + g + 20) * D_ + coff);
            if (b1) t1 = *(const float4*)(feat + (row0 + g + 24) * D_ + coff);
            if (b2) t2 = *(const float4*)(feat + (row0 + g + 28) * D_ + coff);
            if (b0) *(float4*)&rowbuf[(g + 20) * D_ + coff] = t0;
            if (b1) *(float4*)&rowbuf[(g + 24) * D_ + coff] = t1;
            if (b2) *(float4*)&rowbuf[(g + 28) * D_ + coff] = t2;
        }
        __syncthreads();                    // (B1) rowbuf complete

        // ---- sweep2: dot my row-pairs (kw in regs, rows from LDS)
        if (g < width)      dot_pair(g,      width);
        if (g +  8 < width) dot_pair(g +  8, width);
        if (g + 16 < width) dot_pair(g + 16, width);
        if (g + 24 < width) dot_pair(g + 24, width);
        __syncthreads();                    // (B2) wts complete; next pop visible

        // ---- read next span; issue its prefetch NOW (flies over softmax+p3)
        const int snext = (int)s_slot[(it + 1) & 1];
        const bool havenext = (snext < NSPAN);
        int width_n = 0; size_t row0_n = 0;
        if (havenext) {
            const int bg = begins[snext];
            width_n = ends[snext] - bg;
            row0_n  = (size_t)(snext >> 7) * T_ + bg;
            if (g < width_n)     pf0 = *(const float4*)(feat + (row0_n + g)     * D_ + coff);
            if (g + 4 < width_n) pf1 = *(const float4*)(feat + (row0_n + g + 4) * D_ + coff);
        }

        // ---- wave-0 register softmax over wts (proven, in place)
        if (tid < 64) {
            float4 lv = *(const float4*)&wts[lane * 4];
            const int w8 = width * H_;
            float v0 = (4 * lane + 0 < w8) ? lv.x : -1e30f;
            float v1 = (4 * lane + 1 < w8) ? lv.y : -1e30f;
            float v2 = (4 * lane + 2 < w8) ? lv.z : -1e30f;
            float v3 = (4 * lane + 3 < w8) ? lv.w : -1e30f;

            float m0 = v0, m1 = v1, m2 = v2, m3 = v3;
#pragma unroll
            for (int off = 2; off <= 32; off <<= 1) {
                m0 = fmaxf(m0, __shfl_xor(m0, off, 64));
                m1 = fmaxf(m1, __shfl_xor(m1, off, 64));
                m2 = fmaxf(m2, __shfl_xor(m2, off, 64));
                m3 = fmaxf(m3, __shfl_xor(m3, off, 64));
            }
            float e0 = __expf(v0 - m0);     // masked -> exactly 0
            float e1 = __expf(v1 - m1);
            float e2 = __expf(v2 - m2);
            float e3 = __expf(v3 - m3);
            float s0 = e0, s1 = e1, s2 = e2, s3 = e3;
#pragma unroll
            for (int off = 2; off <= 32; off <<= 1) {
                s0 += __shfl_xor(s0, off, 64);
                s1 += __shfl_xor(s1, off, 64);
                s2 += __shfl_xor(s2, off, 64);
                s3 += __shfl_xor(s3, off, 64);
            }
            *(float4*)&wts[lane * 4] =
                make_float4(e0 / s0, e1 / s1, e2 / s2, e3 / s3);
        }
        __syncthreads();                    // (C) weights ready

        // ---- phase 3: threads 0..255, thread t owns cols 4t..4t+3 (one head)
        if (tid < 256) {
            const int ha = tid >> 5;        // head of cols 4t..4t+3
            float4 a = make_float4(0.f, 0.f, 0.f, 0.f);
#pragma unroll 4
            for (int k = 0; k < width; ++k) {
                const float4 rv = *(const float4*)&rowbuf[k * D_ + tid * 4];
                const float wt = wts[k * H_ + ha];
                a.x += wt * rv.x; a.y += wt * rv.y;
                a.z += wt * rv.z; a.w += wt * rv.w;
            }
            *(float4*)(out + (size_t)s * D_ + tid * 4) = a;
        }
        __syncthreads();                    // (A) rowbuf/wts free for next stash

        s = snext; have = havenext; width = width_n; row0 = row0_n; ++it;
    }
}

extern "C" void kernel_launch(void* const* d_in, const int* in_sizes, int n_in,
                              void* d_out, int out_size, void* d_ws, size_t ws_size,
                              hipStream_t stream) {
    const float* feat   = (const float*)d_in[0];   // features f32 [B,T,D]
    const int*   begins = (const int*)d_in[1];     // int32 [B,S]
    const int*   ends   = (const int*)d_in[2];     // int32 [B,S]
    const float* kw     = (const float*)d_in[3];   // key_w f32 [H,D]
    const float* kb     = (const float*)d_in[4];   // key_b f32 [H]
    float*       out    = (float*)d_out;           // f32 [B*S, D]
    unsigned int* counter = (unsigned int*)d_ws;   // 4 B of ws (poison unconditional)

    init_counter<<<1, 1, 0, stream>>>(counter);
    span_pool_v7<<<NBLK, 1024, 0, stream>>>(feat, begins, ends, kw, kb, out, counter);
}

// Round 12
// 111.557 us; speedup vs baseline: 1.1802x; 1.0843x over previous
//
#include <hip/hip_runtime.h>

// Problem constants (fixed by setup_inputs in the reference)
#define B_  8
#define T_  2048
#define D_  1024
#define H_  8
#define S_  128

// --------------------------------------------------------------------------
// R19 = R18 (v10) resubmitted verbatim: R11 died on container acquisition
// ("MI355X container failed twice"), the same infra signature as R5; the
// R5->R6 precedent (verbatim resubmit ran fine) applies. v10 has no hang
// class: no atomics, no spin, no cross-block sync; coverage test is
// wave-uniform; early-exit is after the only barrier.
//
// v10: proven R0 split (108.8 us) + ONE lever from fused-family counters:
// R6/R7 measured FETCH ~37 MB = unique span-covered row footprint (~58% of
// rows). K1 blindly read all 64 MB. v10's K1 wave tests the batch's 128
// spans across its 64 lanes (2 per lane), __any -> covered; uncovered waves
// skip the 4KB row load + dot + logit write (barrier still uniform).
// K2 is VERBATIM R0: masks rows >= width to -1e30 BEFORE any arithmetic,
// so never-written (poison) logit slots are select-replaced, never used.
// Predicted: K1 fetch 64 -> ~40 MB, K1 ~10.4 -> ~7 us, total ~104-106.
// --------------------------------------------------------------------------
__global__ __launch_bounds__(1024) void logits_kernel(
    const float* __restrict__ feat,    // [B*T, D]
    const int* __restrict__ begins,    // [B*S]
    const int* __restrict__ ends,      // [B*S]
    const float* __restrict__ kw,      // [H, D]
    const float* __restrict__ kb,      // [H]
    float* __restrict__ logits)        // [B*T, H]
{
    const int wv   = threadIdx.x >> 6;      // 0..15
    const int lane = threadIdx.x & 63;
    const int row  = blockIdx.x * 16 + wv;  // 1024 blocks -> rows 0..16383

    __shared__ __align__(16) float kwl[H_ * D_];  // 32 KB staged key_w

    {   // stage kw: 1024 threads x 2 float4 (coalesced)
        const float4* src = (const float4*)kw;
        float4*       dst = (float4*)kwl;
        dst[threadIdx.x]        = src[threadIdx.x];
        dst[threadIdx.x + 1024] = src[threadIdx.x + 1024];
    }

    // ---- coverage test: does ANY span of this batch contain this row?
    // (16-row blocks never straddle the 2048-row batch boundary.)
    const int b    = row >> 11;             // batch
    const int tloc = row & 2047;            // local position
    const int s0   = (b << 7) + lane;       // spans lane, lane+64
    const bool hit = (begins[s0]      <= tloc && tloc < ends[s0]) ||
                     (begins[s0 + 64] <= tloc && tloc < ends[s0 + 64]);
    const bool covered = __any(hit);        // wave-wide (64 lanes)

    // Row loads issued BEFORE the barrier (independent of LDS staging);
    // skipped entirely for uncovered rows (the 42% HBM saving).
    const float* fr = feat + (size_t)row * D_;
    float4 fv0, fv1, fv2, fv3;
    if (covered) {
        fv0 = *(const float4*)(fr +   0 + lane * 4);
        fv1 = *(const float4*)(fr + 256 + lane * 4);
        fv2 = *(const float4*)(fr + 512 + lane * 4);
        fv3 = *(const float4*)(fr + 768 + lane * 4);
    }

    __syncthreads();

    if (!covered) return;                   // after the barrier: uniform exit ok

    float acc[H_];
#pragma unroll
    for (int h = 0; h < H_; ++h) {
        const float* kh = &kwl[h * D_ + lane * 4];
        float4 k0 = *(const float4*)(kh +   0);
        float4 k1 = *(const float4*)(kh + 256);
        float4 k2 = *(const float4*)(kh + 512);
        float4 k3 = *(const float4*)(kh + 768);
        acc[h] = fv0.x * k0.x + fv0.y * k0.y + fv0.z * k0.z + fv0.w * k0.w
               + fv1.x * k1.x + fv1.y * k1.y + fv1.z * k1.z + fv1.w * k1.w
               + fv2.x * k2.x + fv2.y * k2.y + fv2.z * k2.z + fv2.w * k2.w
               + fv3.x * k3.x + fv3.y * k3.y + fv3.z * k3.z + fv3.w * k3.w;
    }

    // Value-compacting reduce over lane bits 0..2 (4+2+1 = 7 shuffles)
#pragma unroll
    for (int s = 0; s < 3; ++s) {
        const int m = 1 << s;
        const bool hi = (lane >> s) & 1;
#pragma unroll
        for (int j = 0; j < (4 >> s); ++j) {
            float mine  = hi ? acc[2 * j + 1] : acc[2 * j];
            float other = hi ? acc[2 * j]     : acc[2 * j + 1];
            acc[j] = mine + __shfl_xor(other, m, 64);
        }
    }
    acc[0] += __shfl_xor(acc[0],  8, 64);
    acc[0] += __shfl_xor(acc[0], 16, 64);
    acc[0] += __shfl_xor(acc[0], 32, 64);

    if (lane < H_)
        logits[(size_t)row * H_ + lane] = acc[0] + kb[lane];
}

// --------------------------------------------------------------------------
// K2: VERBATIM from R0 (proven at 108.8 us). One block per (span, quarter).
// 4096 blocks x 256 threads -> 8 blocks/CU, 32 waves/CU.
// --------------------------------------------------------------------------
__global__ __launch_bounds__(256) void pool_kernel(
    const float* __restrict__ feat,    // [B*T, D]
    const int* __restrict__ begins,    // [B*S]
    const int* __restrict__ ends,      // [B*S]
    const float* __restrict__ logits,  // [B*T, H]
    float* __restrict__ out)           // [B*S, D]
{
    const int blk  = blockIdx.x;            // bs*4 + q
    const int bs   = blk >> 2;
    const int q    = blk & 3;
    const int wv   = threadIdx.x >> 6;      // row-chunk 0..3
    const int lane = threadIdx.x & 63;
    const int b    = bs >> 7;               // / S_

    const int begin = begins[bs];
    const int width = ends[bs] - begin;     // 1..32
    const size_t row0 = (size_t)b * T_ + begin;

    __shared__ __align__(16) float wslab[256];        // weights [i*8+h]
    __shared__ __align__(16) float pslab[4 * 256];    // per-wave partials

    // ---- issue this wave's span-row loads first (they don't need weights)
    const int colbase = q * 256 + lane * 4;
    const float* fbase = feat + row0 * D_ + colbase;
    const bool active = (wv * 8) < width;
    float4 fv[8];
    if (active) {
#pragma unroll
        for (int k = 0; k < 8; ++k)
            fv[k] = *(const float4*)(fbase + (size_t)(wv * 8 + k) * D_);
    }

    // ---- wave 0: span softmax -> wslab (loads above already in flight)
    if (wv == 0) {
        float4 lv = *(const float4*)(logits + row0 * H_ + lane * 4);
        const int w8 = width * H_;
        float v0 = (4 * lane + 0 < w8) ? lv.x : -1e30f;
        float v1 = (4 * lane + 1 < w8) ? lv.y : -1e30f;
        float v2 = (4 * lane + 2 < w8) ? lv.z : -1e30f;
        float v3 = (4 * lane + 3 < w8) ? lv.w : -1e30f;

        float m0 = v0, m1 = v1, m2 = v2, m3 = v3;
#pragma unroll
        for (int off = 2; off <= 32; off <<= 1) {
            m0 = fmaxf(m0, __shfl_xor(m0, off, 64));
            m1 = fmaxf(m1, __shfl_xor(m1, off, 64));
            m2 = fmaxf(m2, __shfl_xor(m2, off, 64));
            m3 = fmaxf(m3, __shfl_xor(m3, off, 64));
        }
        float e0 = __expf(v0 - m0);          // masked -> exactly 0
        float e1 = __expf(v1 - m1);
        float e2 = __expf(v2 - m2);
        float e3 = __expf(v3 - m3);
        float s0 = e0, s1 = e1, s2 = e2, s3 = e3;
#pragma unroll
        for (int off = 2; off <= 32; off <<= 1) {
            s0 += __shfl_xor(s0, off, 64);
            s1 += __shfl_xor(s1, off, 64);
            s2 += __shfl_xor(s2, off, 64);
            s3 += __shfl_xor(s3, off, 64);
        }
        *(float4*)&wslab[lane * 4] =
            make_float4(e0 / s0, e1 / s1, e2 / s2, e3 / s3);
    }
    __syncthreads();

    // ---- weighted accumulate (weights via LDS half-wave broadcast)
    float4 acc = make_float4(0.f, 0.f, 0.f, 0.f);
    if (active) {
        const int hoff = 2 * q + (lane >= 32 ? 1 : 0);  // head for my cols
#pragma unroll
        for (int k = 0; k < 8; ++k) {
            const float wt = wslab[(wv * 8 + k) * 8 + hoff];
            acc.x += wt * fv[k].x;
            acc.y += wt * fv[k].y;
            acc.z += wt * fv[k].z;
            acc.w += wt * fv[k].w;
        }
    }
    *(float4*)&pslab[wv * 256 + lane * 4] = acc;   // inactive waves write 0
    __syncthreads();

    // ---- wave 0: reduce 4 partials, store 1 KB coalesced
    if (wv == 0) {
        float4 r0 = *(const float4*)&pslab[0 * 256 + lane * 4];
        float4 r1 = *(const float4*)&pslab[1 * 256 + lane * 4];
        float4 r2 = *(const float4*)&pslab[2 * 256 + lane * 4];
        float4 r3 = *(const float4*)&pslab[3 * 256 + lane * 4];
        float4 o = make_float4(r0.x + r1.x + r2.x + r3.x,
                               r0.y + r1.y + r2.y + r3.y,
                               r0.z + r1.z + r2.z + r3.z,
                               r0.w + r1.w + r2.w + r3.w);
        *(float4*)(out + (size_t)bs * D_ + colbase) = o;
    }
}

extern "C" void kernel_launch(void* const* d_in, const int* in_sizes, int n_in,
                              void* d_out, int out_size, void* d_ws, size_t ws_size,
                              hipStream_t stream) {
    const float* feat   = (const float*)d_in[0];   // features f32 [B,T,D]
    const int*   begins = (const int*)d_in[1];     // int32 [B,S]
    const int*   ends   = (const int*)d_in[2];     // int32 [B,S]
    const float* kw     = (const float*)d_in[3];   // key_w f32 [H,D]
    const float* kb     = (const float*)d_in[4];   // key_b f32 [H]
    float*       out    = (float*)d_out;           // f32 [B*S, D]
    float* logits = (float*)d_ws;                  // 16384*8*4 = 512 KB scratch

    logits_kernel<<<1024, 1024, 0, stream>>>(feat, begins, ends, kw, kb, logits);
    pool_kernel<<<B_ * S_ * 4, 256, 0, stream>>>(feat, begins, ends, logits, out);
}